// Round 2
// baseline (85.614 us; speedup 1.0000x reference)
//
#include <hip/hip_runtime.h>

#define NQ 8
#define NL 4
#define BATCH 4096
#define DIM 256

// ---------------------------------------------------------------------------
// Wave-per-state simulator helpers (64 lanes = 1 state of 256 amps).
// Amp index a = (lane << 2) | r. Wire i <-> bit (7 - i) of a.
// Bits 2..7 of a = lane bits 0..5 (cross-lane via shfl_xor); bits 0..1 = regs.
// ---------------------------------------------------------------------------

__device__ __forceinline__ void apply_ry(float re[4], float im[4], int b,
                                         float c, float s, int lane) {
  if (b >= 2) {
    const int m = 1 << (b - 2);
    const float ss = (lane & m) ? s : -s;
#pragma unroll
    for (int r = 0; r < 4; ++r) {
      float pr = __shfl_xor(re[r], m, 64);
      float pi = __shfl_xor(im[r], m, 64);
      re[r] = c * re[r] + ss * pr;
      im[r] = c * im[r] + ss * pi;
    }
  } else {
    const int p0a = 0, p1a = (b == 0) ? 1 : 2;
    const int p0b = (b == 0) ? 2 : 1, p1b = 3;
    {
      float n0r = c * re[p0a] - s * re[p1a], n1r = s * re[p0a] + c * re[p1a];
      float n0i = c * im[p0a] - s * im[p1a], n1i = s * im[p0a] + c * im[p1a];
      re[p0a] = n0r; re[p1a] = n1r; im[p0a] = n0i; im[p1a] = n1i;
    }
    {
      float n0r = c * re[p0b] - s * re[p1b], n1r = s * re[p0b] + c * re[p1b];
      float n0i = c * im[p0b] - s * im[p1b], n1i = s * im[p0b] + c * im[p1b];
      re[p0b] = n0r; re[p1b] = n1r; im[p0b] = n0i; im[p1b] = n1i;
    }
  }
}

__device__ __forceinline__ void apply_rz(float re[4], float im[4], int b,
                                         float c, float s, int lane) {
  if (b >= 2) {
    const int m = 1 << (b - 2);
    const float ss = (lane & m) ? s : -s;
#pragma unroll
    for (int r = 0; r < 4; ++r) {
      float nr = re[r] * c - im[r] * ss;
      float ni = im[r] * c + re[r] * ss;
      re[r] = nr; im[r] = ni;
    }
  } else {
#pragma unroll
    for (int r = 0; r < 4; ++r) {
      const float ss = ((r >> b) & 1) ? s : -s;
      float nr = re[r] * c - im[r] * ss;
      float ni = im[r] * c + re[r] * ss;
      re[r] = nr; im[r] = ni;
    }
  }
}

__device__ __forceinline__ void cswap_pair(float re[4], float im[4],
                                           int p0, int p1, bool ctrl) {
  float r0 = re[p0], r1 = re[p1], i0 = im[p0], i1 = im[p1];
  re[p0] = ctrl ? r1 : r0; re[p1] = ctrl ? r0 : r1;
  im[p0] = ctrl ? i1 : i0; im[p1] = ctrl ? i0 : i1;
}

__device__ __forceinline__ void apply_cnot(float re[4], float im[4],
                                           int bc, int bt, int lane) {
  if (bt >= 2) {
    const int mt = 1 << (bt - 2);
#pragma unroll
    for (int r = 0; r < 4; ++r) {
      float pr = __shfl_xor(re[r], mt, 64);
      float pi = __shfl_xor(im[r], mt, 64);
      bool ctrl = (bc >= 2) ? (((lane >> (bc - 2)) & 1) != 0)
                            : (((r >> bc) & 1) != 0);
      re[r] = ctrl ? pr : re[r];
      im[r] = ctrl ? pi : im[r];
    }
  } else {
    const int q0a = 0, q1a = (bt == 0) ? 1 : 2;
    const int q0b = (bt == 0) ? 2 : 1, q1b = 3;
    bool ca, cb;
    if (bc >= 2) {
      bool c = ((lane >> (bc - 2)) & 1) != 0;
      ca = c; cb = c;
    } else {
      ca = ((q0a >> bc) & 1) != 0;
      cb = ((q0b >> bc) & 1) != 0;
    }
    cswap_pair(re, im, q0a, q1a, ca);
    cswap_pair(re, im, q0b, q1b, cb);
  }
}

// ---------------------------------------------------------------------------
// Kernel A: apply the fixed variational circuit V to each of the 256 basis
// states. Wave b computes u_b = V|b>; stores Ar[b][k] = Re u_b[k],
// Ai[b][k] = Im u_b[k] (rows contiguous in k).
// ---------------------------------------------------------------------------
__global__ __launch_bounds__(256) void basis_kernel(const float* __restrict__ w,
                                                    float* __restrict__ Ar,
                                                    float* __restrict__ Ai) {
  const int b = (int)((blockIdx.x * blockDim.x + threadIdx.x) >> 6);
  const int lane = (int)(threadIdx.x & 63);

  float re[4], im[4];
#pragma unroll
  for (int r = 0; r < 4; ++r) { re[r] = 0.f; im[r] = 0.f; }
  if (lane == (b >> 2)) re[b & 3] = 1.f;   // |b>

#pragma unroll
  for (int l = 0; l < NL; ++l) {
#pragma unroll
    for (int i = 0; i < NQ; ++i) {
      int bc = 7 - i;
      int bt = 7 - ((i + 1) & (NQ - 1));
      apply_cnot(re, im, bc, bt, lane);
    }
#pragma unroll
    for (int i = 0; i < NQ; ++i) {
      float ty = w[(l * NQ + i) * 2 + 0] * 0.5f;
      float tz = w[(l * NQ + i) * 2 + 1] * 0.5f;
      float sy, cy, sz, cz;
      __sincosf(ty, &sy, &cy);
      __sincosf(tz, &sz, &cz);
      apply_ry(re, im, 7 - i, cy, sy, lane);
      apply_rz(re, im, 7 - i, cz, sz, lane);
    }
  }

  float4 vr = make_float4(re[0], re[1], re[2], re[3]);
  float4 vi = make_float4(im[0], im[1], im[2], im[3]);
  *(float4*)&Ar[b * DIM + lane * 4] = vr;
  *(float4*)&Ai[b * DIM + lane * 4] = vi;
}

// ---------------------------------------------------------------------------
// Kernel C1: encoded product state Psi[s][a] = prod_i (bit_{7-i}(a) ? sin : cos)
// of x_i/2 (real). Also zeroes out[s] for the atomic epilogue of C2.
// ---------------------------------------------------------------------------
__global__ __launch_bounds__(256) void psi_kernel(const float* __restrict__ x,
                                                  float* __restrict__ Psi,
                                                  float* __restrict__ out) {
  const int s = (int)((blockIdx.x * blockDim.x + threadIdx.x) >> 6);
  const int lane = (int)(threadIdx.x & 63);

  float cv[NQ], sv[NQ];
#pragma unroll
  for (int i = 0; i < NQ; ++i) {
    __sincosf(x[s * NQ + i] * 0.5f, &sv[i], &cv[i]);
  }

  float4 v;
  float* pv = (float*)&v;
#pragma unroll
  for (int r = 0; r < 4; ++r) {
    int a = lane * 4 + r;
    float p = 1.f;
#pragma unroll
    for (int j = 0; j < NQ; ++j) {       // bit j of a is wire 7-j
      p *= ((a >> j) & 1) ? sv[7 - j] : cv[7 - j];
    }
    pv[r] = p;
  }
  *(float4*)&Psi[s * DIM + lane * 4] = v;
  if (lane == 0) out[s] = 0.f;
}

// ---------------------------------------------------------------------------
// Kernel C2: Phi_r = Psi * Ar, Phi_i = Psi * Ai (K = basis index b), fused
// epilogue out[s] += sign(k) * (phi_r^2 + phi_i^2) summed over this block's
// 64 k-columns. Block = 64 samples x 64 k-cols, 512 threads, Kt = 32.
// ---------------------------------------------------------------------------
#define PS_STRIDE 36

__global__ __launch_bounds__(512) void gemm_kernel(const float* __restrict__ Psi,
                                                   const float* __restrict__ Ar,
                                                   const float* __restrict__ Ai,
                                                   float* __restrict__ out) {
  __shared__ float Ps[64 * PS_STRIDE];
  __shared__ float Brs[32 * 64];
  __shared__ float Bis[32 * 64];
  __shared__ float red[64];

  const int tid = (int)threadIdx.x;
  const int tx = tid & 15;        // k-col group: cols tx*4 .. +3
  const int ty = tid >> 4;        // sample group: rows ty*2 .. +1
  const int sm = (int)blockIdx.x * 64;
  const int kn = (int)blockIdx.y * 64;

  float accr[2][4], acci[2][4];
#pragma unroll
  for (int rr = 0; rr < 2; ++rr)
#pragma unroll
    for (int c = 0; c < 4; ++c) { accr[rr][c] = 0.f; acci[rr][c] = 0.f; }

  for (int b0 = 0; b0 < DIM; b0 += 32) {
    __syncthreads();
    {
      int row = tid >> 3, k4 = (tid & 7) * 4;   // 64 rows x 32 k
      float4 v = *(const float4*)&Psi[(sm + row) * DIM + b0 + k4];
      *(float4*)&Ps[row * PS_STRIDE + k4] = v;
    }
    {
      int kk = tid >> 4, c4 = (tid & 15) * 4;   // 32 k x 64 cols
      *(float4*)&Brs[kk * 64 + c4] = *(const float4*)&Ar[(b0 + kk) * DIM + kn + c4];
      *(float4*)&Bis[kk * 64 + c4] = *(const float4*)&Ai[(b0 + kk) * DIM + kn + c4];
    }
    __syncthreads();

#pragma unroll 8
    for (int kk = 0; kk < 32; ++kk) {
      float a0 = Ps[(ty * 2 + 0) * PS_STRIDE + kk];
      float a1 = Ps[(ty * 2 + 1) * PS_STRIDE + kk];
      const float4 br = *(const float4*)&Brs[kk * 64 + tx * 4];
      const float4 bi = *(const float4*)&Bis[kk * 64 + tx * 4];
      const float brv[4] = {br.x, br.y, br.z, br.w};
      const float biv[4] = {bi.x, bi.y, bi.z, bi.w};
#pragma unroll
      for (int c = 0; c < 4; ++c) {
        accr[0][c] = fmaf(a0, brv[c], accr[0][c]);
        accr[1][c] = fmaf(a1, brv[c], accr[1][c]);
        acci[0][c] = fmaf(a0, biv[c], acci[0][c]);
        acci[1][c] = fmaf(a1, biv[c], acci[1][c]);
      }
    }
  }

  // epilogue: per-thread |phi|^2 partial over 4 cols, reduce per sample in LDS
  if (tid < 64) red[tid] = 0.f;
  __syncthreads();
  float v0 = 0.f, v1 = 0.f;
#pragma unroll
  for (int c = 0; c < 4; ++c) {
    v0 += accr[0][c] * accr[0][c] + acci[0][c] * acci[0][c];
    v1 += accr[1][c] * accr[1][c] + acci[1][c] * acci[1][c];
  }
  atomicAdd(&red[ty * 2 + 0], v0);
  atomicAdd(&red[ty * 2 + 1], v1);
  __syncthreads();

  const float sgn = (kn & 128) ? -1.f : 1.f;  // qubit 0 = bit 7 of k
  if (tid < 64) atomicAdd(&out[sm + tid], sgn * red[tid]);
}

// ---------------------------------------------------------------------------
extern "C" void kernel_launch(void* const* d_in, const int* in_sizes, int n_in,
                              void* d_out, int out_size, void* d_ws, size_t ws_size,
                              hipStream_t stream) {
  const float* x = (const float*)d_in[0];   // (4096, 8) f32
  const float* w = (const float*)d_in[1];   // (4, 8, 2) f32
  float* out = (float*)d_out;               // (4096,) f32
  (void)in_sizes; (void)n_in; (void)out_size; (void)ws_size;

  float* Ar  = (float*)d_ws;                       // 256*256 f32 = 256 KB
  float* Ai  = Ar + DIM * DIM;                     // 256 KB
  float* Psi = Ai + DIM * DIM;                     // 4096*256 f32 = 4 MB

  // A: V on basis states — 256 waves
  hipLaunchKernelGGL(basis_kernel, dim3(64), dim3(256), 0, stream, w, Ar, Ai);
  // C1: product-state amplitudes + zero out — 4096 waves
  hipLaunchKernelGGL(psi_kernel, dim3(BATCH / 4), dim3(256), 0, stream, x, Psi, out);
  // C2: fused GEMM + |.|^2 epilogue — 64 x 4 blocks
  hipLaunchKernelGGL(gemm_kernel, dim3(BATCH / 64, DIM / 64), dim3(512), 0, stream,
                     Psi, Ar, Ai, out);
}

// Round 3
// 65.389 us; speedup vs baseline: 1.3093x; 1.3093x over previous
//
#include <hip/hip_runtime.h>

#define NQ 8
#define NL 4
#define BATCH 4096

// ---------------------------------------------------------------------------
// Layout: one wave = 4 samples. Each 16-lane group holds one sample's 256
// amps: amp index a = (g << 4) | r, g = lane & 15, r = register index 0..15.
// Wire i of the reference <-> bit (7 - i) of a (C-order flatten, wire 0 MSB):
//   wire 0..3 <-> g bits 3..0   (cross-lane: xor masks 8,4,2,1)
//   wire 4..7 <-> r bits 3..0   (pure register ops)
// Cross-lane exchange: masks 1,2 via DPP quad_perm, mask 8 via DPP row_ror:8
// (rotation by 8 within a 16-lane row == xor 8). Only mask 4 needs ds_swizzle.
// ---------------------------------------------------------------------------

template <int CTRL>
__device__ __forceinline__ float dppx(float v) {
  return __int_as_float(
      __builtin_amdgcn_update_dpp(0, __float_as_int(v), CTRL, 0xF, 0xF, true));
}

__device__ __forceinline__ float swz4(float v) {   // lane ^ 4
  return __int_as_float(
      __builtin_amdgcn_ds_swizzle(__float_as_int(v), 0x101F));
}

// lane exchange along wire W (0..3): partner differs in lane bit (3-W)
template <int W>
__device__ __forceinline__ float xl(float v) {
  if constexpr (W == 0) return dppx<0x128>(v);       // row_ror:8  == lane^8
  else if constexpr (W == 1) return swz4(v);         // lane^4
  else if constexpr (W == 2) return dppx<0x4E>(v);   // quad_perm [2,3,0,1] == lane^2
  else return dppx<0xB1>(v);                         // quad_perm [1,0,3,2] == lane^1
}

template <int W>
__device__ __forceinline__ void ry_gate(float re[16], float im[16],
                                        float c, float s, int lane) {
  if constexpr (W <= 3) {
    const float ss = ((lane >> (3 - W)) & 1) ? s : -s;
#pragma unroll
    for (int r = 0; r < 16; ++r) {
      float pr = xl<W>(re[r]);
      float pi = xl<W>(im[r]);
      re[r] = c * re[r] + ss * pr;
      im[r] = c * im[r] + ss * pi;
    }
  } else {
    constexpr int m = 1 << (7 - W);
#pragma unroll
    for (int r = 0; r < 16; ++r) {
      if ((r & m) == 0) {
        const int r1 = r | m;
        float a0r = re[r], a1r = re[r1];
        float a0i = im[r], a1i = im[r1];
        re[r]  = c * a0r - s * a1r;
        re[r1] = s * a0r + c * a1r;
        im[r]  = c * a0i - s * a1i;
        im[r1] = s * a0i + c * a1i;
      }
    }
  }
}

template <int W>
__device__ __forceinline__ void rz_gate(float re[16], float im[16],
                                        float c, float s, int lane) {
  // amp *= (c - i s) when wire-bit 0, (c + i s) when wire-bit 1; no data motion
  if constexpr (W <= 3) {
    const float ss = ((lane >> (3 - W)) & 1) ? s : -s;
#pragma unroll
    for (int r = 0; r < 16; ++r) {
      float nr = re[r] * c - im[r] * ss;
      float ni = im[r] * c + re[r] * ss;
      re[r] = nr; im[r] = ni;
    }
  } else {
    constexpr int m = 1 << (7 - W);
#pragma unroll
    for (int r = 0; r < 16; ++r) {
      const float ss = (r & m) ? s : -s;  // compile-time sign per register
      float nr = re[r] * c - im[r] * ss;
      float ni = im[r] * c + re[r] * ss;
      re[r] = nr; im[r] = ni;
    }
  }
}

__device__ __forceinline__ void cnot_ring(float re[16], float im[16], int lane) {
  // CNOT(0,1): ctrl lane bit3, tgt lane bit2 (xor4 swizzle)
  {
    const bool p = (lane & 8) != 0;
#pragma unroll
    for (int r = 0; r < 16; ++r) {
      float pr = swz4(re[r]), pi = swz4(im[r]);
      re[r] = p ? pr : re[r];
      im[r] = p ? pi : im[r];
    }
  }
  // CNOT(1,2): ctrl lane bit2, tgt lane bit1 (xor2 DPP)
  {
    const bool p = (lane & 4) != 0;
#pragma unroll
    for (int r = 0; r < 16; ++r) {
      float pr = dppx<0x4E>(re[r]), pi = dppx<0x4E>(im[r]);
      re[r] = p ? pr : re[r];
      im[r] = p ? pi : im[r];
    }
  }
  // CNOT(2,3): ctrl lane bit1, tgt lane bit0 (xor1 DPP)
  {
    const bool p = (lane & 2) != 0;
#pragma unroll
    for (int r = 0; r < 16; ++r) {
      float pr = dppx<0xB1>(re[r]), pi = dppx<0xB1>(im[r]);
      re[r] = p ? pr : re[r];
      im[r] = p ? pi : im[r];
    }
  }
  // CNOT(3,4): ctrl lane bit0, tgt reg bit3 — predicated register swap
  {
    const bool p = (lane & 1) != 0;
#pragma unroll
    for (int r = 0; r < 8; ++r) {
      float t0r = re[r], t1r = re[r + 8];
      re[r] = p ? t1r : t0r; re[r + 8] = p ? t0r : t1r;
      float t0i = im[r], t1i = im[r + 8];
      im[r] = p ? t1i : t0i; im[r + 8] = p ? t0i : t1i;
    }
  }
  // CNOT(4,5): ctrl reg bit3, tgt reg bit2 — compile-time rename
#pragma unroll
  for (int r = 8; r < 12; ++r) {
    float t = re[r]; re[r] = re[r + 4]; re[r + 4] = t;
    t = im[r]; im[r] = im[r + 4]; im[r + 4] = t;
  }
  // CNOT(5,6): ctrl reg bit2, tgt reg bit1 — compile-time rename
#pragma unroll
  for (int r = 0; r < 16; ++r) {
    if ((r & 4) && !(r & 2)) {
      float t = re[r]; re[r] = re[r | 2]; re[r | 2] = t;
      t = im[r]; im[r] = im[r | 2]; im[r | 2] = t;
    }
  }
  // CNOT(6,7): ctrl reg bit1, tgt reg bit0 — compile-time rename
#pragma unroll
  for (int r = 0; r < 16; ++r) {
    if ((r & 2) && !(r & 1)) {
      float t = re[r]; re[r] = re[r | 1]; re[r | 1] = t;
      t = im[r]; im[r] = im[r | 1]; im[r | 1] = t;
    }
  }
  // CNOT(7,0): ctrl reg bit0, tgt lane bit3 — odd regs take their xor8 partner
#pragma unroll
  for (int r = 1; r < 16; r += 2) {
    re[r] = dppx<0x128>(re[r]);
    im[r] = dppx<0x128>(im[r]);
  }
}

__global__ __launch_bounds__(256) void vqc_kernel(const float* __restrict__ x,
                                                  const float* __restrict__ w,
                                                  float* __restrict__ out) {
  const int lane = (int)(threadIdx.x & 63);
  const int wv = (int)((blockIdx.x * blockDim.x + threadIdx.x) >> 6);
  const int s = wv * 4 + (lane >> 4);   // this 16-lane group's sample

  float re[16], im[16];
#pragma unroll
  for (int r = 0; r < 16; ++r) { re[r] = 0.f; im[r] = 0.f; }
  if ((lane & 15) == 0) re[0] = 1.f;    // |0...0> = amp 0 (g=0, r=0)

  // Angle encoding: RY(x_i) on wire i (rotations on distinct wires commute)
  {
    const float4 x0 = *(const float4*)&x[s * 8];
    const float4 x1 = *(const float4*)&x[s * 8 + 4];
    float c, sn;
    __sincosf(x0.x * 0.5f, &sn, &c); ry_gate<0>(re, im, c, sn, lane);
    __sincosf(x0.y * 0.5f, &sn, &c); ry_gate<1>(re, im, c, sn, lane);
    __sincosf(x0.z * 0.5f, &sn, &c); ry_gate<2>(re, im, c, sn, lane);
    __sincosf(x0.w * 0.5f, &sn, &c); ry_gate<3>(re, im, c, sn, lane);
    __sincosf(x1.x * 0.5f, &sn, &c); ry_gate<4>(re, im, c, sn, lane);
    __sincosf(x1.y * 0.5f, &sn, &c); ry_gate<5>(re, im, c, sn, lane);
    __sincosf(x1.z * 0.5f, &sn, &c); ry_gate<6>(re, im, c, sn, lane);
    __sincosf(x1.w * 0.5f, &sn, &c); ry_gate<7>(re, im, c, sn, lane);
  }

#pragma unroll
  for (int l = 0; l < NL; ++l) {
    cnot_ring(re, im, lane);
    const float* wl = &w[l * NQ * 2];
#define APPLY_ROT(W) { float cy, sy, cz, sz;            \
    __sincosf(wl[(W) * 2 + 0] * 0.5f, &sy, &cy);        \
    __sincosf(wl[(W) * 2 + 1] * 0.5f, &sz, &cz);        \
    ry_gate<W>(re, im, cy, sy, lane);                   \
    rz_gate<W>(re, im, cz, sz, lane); }
    APPLY_ROT(0) APPLY_ROT(1) APPLY_ROT(2) APPLY_ROT(3)
    APPLY_ROT(4) APPLY_ROT(5) APPLY_ROT(6) APPLY_ROT(7)
#undef APPLY_ROT
  }

  // <Z_0>: wire 0 = amp bit 7 = lane bit 3; sign then 16-lane reduction
  float acc = 0.f;
#pragma unroll
  for (int r = 0; r < 16; ++r) acc += re[r] * re[r] + im[r] * im[r];
  acc = (lane & 8) ? -acc : acc;
  acc += dppx<0xB1>(acc);   // xor 1
  acc += dppx<0x4E>(acc);   // xor 2
  acc += swz4(acc);         // xor 4
  acc += dppx<0x128>(acc);  // xor 8
  if ((lane & 15) == 0) out[s] = acc;
}

extern "C" void kernel_launch(void* const* d_in, const int* in_sizes, int n_in,
                              void* d_out, int out_size, void* d_ws, size_t ws_size,
                              hipStream_t stream) {
  const float* x = (const float*)d_in[0];   // (4096, 8) f32
  const float* w = (const float*)d_in[1];   // (4, 8, 2) f32
  float* out = (float*)d_out;               // (4096,) f32
  (void)in_sizes; (void)n_in; (void)out_size; (void)d_ws; (void)ws_size;

  // 4 samples per wave: 1024 waves = 256 blocks x 256 threads
  dim3 grid(BATCH / 16), block(256);
  hipLaunchKernelGGL(vqc_kernel, grid, block, 0, stream, x, w, out);
}